// Round 7
// baseline (4538.398 us; speedup 1.0000x reference)
//
#include <hip/hip_runtime.h>
#include <hip/hip_bf16.h>
#include <cstdint>
#include <cstddef>

#define T_STEPS 1024
#define BATCH   128
#define INF     128   // used input features (130 minus last 2)
#define HID     512
#define NBLK    256   // 32 ug x 8 bg ; bg = blk & 7 (XCD-aligned), ug = blk >> 3
#define NTHR    512   // 8 waves: kq = w&3 (160-deep k quarter), th = w>>2 (2 of 4 gates)
#define PK      648   // padded k stride (bf16 units) in LDS Z planes
#define Z_SHORTS    (2 * 16 * PK)            // 20736 shorts = 41472 B
#define GSTR        17
#define GATE_FLOATS (4 * 4 * 16 * GSTR)      // 4352 floats = 17408 B
#define SMEM_BYTES  (Z_SHORTS * 2 + GATE_FLOATS * 4)   // 58880 B

typedef short  bf16x8 __attribute__((ext_vector_type(8)));
typedef float  f32x4  __attribute__((ext_vector_type(4)));

static __device__ __forceinline__ unsigned short bf_hi(float v) {
  __hip_bfloat16 h = __float2bfloat16(v);
  return *reinterpret_cast<unsigned short*>(&h);
}
static __device__ __forceinline__ float bf_val(unsigned short u) {
  __hip_bfloat16 h = *reinterpret_cast<__hip_bfloat16*>(&u);
  return __bfloat162float(h);
}
static __device__ __forceinline__ float fsigmoid(float x) {
  return 1.f / (1.f + __expf(-x));
}
static __device__ __forceinline__ float ftanh(float x) {
  return 1.f - 2.f / (__expf(2.f * x) + 1.f);
}

// ---------------- pre-pass kernels ----------------

// xp[t*8+bg][p][c 16][k 128] bf16 (p=0 hi, p=1 lo)
__global__ __launch_bounds__(256) void k_prep_x(const float* __restrict__ in,
                                                unsigned short* __restrict__ xp)
{
  int t = blockIdx.x >> 3, bg = blockIdx.x & 7;
  int tid = threadIdx.x;
  size_t base = (size_t)blockIdx.x * 4096;
  #pragma unroll
  for (int rep = 0; rep < 8; ++rep) {
    int idx = rep * 256 + tid;           // 0..2047
    int c = idx >> 7, k = idx & 127;
    float v = in[((size_t)(bg * 16 + c) * T_STEPS + t) * 130 + k];
    unsigned short hi = bf_hi(v);
    unsigned short lo = bf_hi(v - bf_val(hi));
    xp[base + c * 128 + k]        = hi;
    xp[base + 2048 + c * 128 + k] = lo;
  }
}

// W A-fragments, bf16 hi/lo, per-lane MFMA layout.
// blk = ((ug*4+q)*4+kq)*5+s   (2560 blocks x 64 threads)
__global__ __launch_bounds__(64) void k_prep_w(const float* __restrict__ Wih,
                                               const float* __restrict__ Whh,
                                               unsigned short* __restrict__ wf)
{
  int blk = blockIdx.x;
  int s = blk % 5; int r = blk / 5;
  int kq = r & 3; int q = (r >> 2) & 3; int ug = r >> 4;
  int l = threadIdx.x;
  int Grow = q * HID + ug * 16 + (l & 15);
  int kb = kq * 160 + s * 32 + (l >> 4) * 8;
  float v[8];
  #pragma unroll
  for (int j = 0; j < 8; ++j)
    v[j] = (kb < INF) ? Wih[(size_t)Grow * INF + kb + j]
                      : Whh[(size_t)Grow * HID + (kb - INF) + j];
  unsigned short hi[8], lo[8];
  #pragma unroll
  for (int j = 0; j < 8; ++j) {
    hi[j] = bf_hi(v[j]);
    lo[j] = bf_hi(v[j] - bf_val(hi[j]));
  }
  unsigned short* dh = wf + ((size_t)(blk * 2 + 0) * 64 + l) * 8;
  unsigned short* dl = wf + ((size_t)(blk * 2 + 1) * 64 + l) * 8;
  #pragma unroll
  for (int j = 0; j < 8; ++j) { dh[j] = hi[j]; dl[j] = lo[j]; }
}

// hp0[bg][c 16][k 512] u32 = hi | lo<<16 of h0[b][k]; zero flags + arrival ctr
__global__ __launch_bounds__(256) void k_prep_h(const float* __restrict__ h0,
                                                unsigned* __restrict__ hp0,
                                                unsigned* __restrict__ flags)
{
  int idx = blockIdx.x * 256 + threadIdx.x;   // 0..65535
  int k = idx & 511, c = (idx >> 9) & 15, bg = idx >> 13;
  float v = h0[(size_t)(bg * 16 + c) * HID + k];
  unsigned short hi = bf_hi(v);
  unsigned short lo = bf_hi(v - bf_val(hi));
  hp0[idx] = (unsigned)hi | ((unsigned)lo << 16);
  if (blockIdx.x == 0 && threadIdx.x < 256) flags[threadIdx.x] = 0;
  if (blockIdx.x == 1 && threadIdx.x < 32)  flags[512 + threadIdx.x] = 0;
}

// ---------------- persistent MFMA LSTM ----------------
// 256 blocks = 32 ug (16 units) x 8 bg (16 b), bg = blk&7 -> one XCD per bg
// (runtime-verified; agent-scope fallback keeps correctness mapping-independent).
__global__ __launch_bounds__(NTHR, 2) void k_persist(
    const unsigned short* __restrict__ xp,   // [t*8+bg][2][16][128]
    const unsigned short* __restrict__ wf,   // A-fragments
    const float* __restrict__ bih, const float* __restrict__ bhh,
    unsigned* __restrict__ hp0,              // [8][16][512] packed hi|lo<<16
    unsigned* __restrict__ hp1,
    const float* __restrict__ c0,            // [128][512]
    const int* __restrict__ len,
    float* __restrict__ out,                 // [128][512]
    unsigned* __restrict__ flags)            // [256] flags | [256] xcds | [1] ctr
{
  extern __shared__ char smem[];
  short* zpl   = (short*)smem;                     // [2][16][PK] bf16
  float* gates = (float*)(smem + Z_SHORTS * 2);    // [4 kq][4 q][16 u][GSTR]
  __shared__ unsigned s_fast;

  const int blk = blockIdx.x;
  const int bg = blk & 7, ug = blk >> 3;
  const int tid = threadIdx.x;
  const int w = tid >> 6, l = tid & 63;
  const int kq = w & 3, th = w >> 2;
  const int cB = l & 15, gch = l >> 4;
  const int q0 = th * 2, q1 = th * 2 + 1;

  // ---- load 20 W A-fragments into NAMED registers (once)
  const uint4* wfq = (const uint4*)wf;
#define LDW(q_, s_, p_) \
  (*reinterpret_cast<const bf16x8*>(&wfq[(size_t)((((ug * 4 + (q_)) * 4 + kq) * 5 + (s_)) * 2 + (p_)) * 64 + l]))
  bf16x8 Aa0h = LDW(q0,0,0), Aa0l = LDW(q0,0,1), Aa1h = LDW(q0,1,0), Aa1l = LDW(q0,1,1);
  bf16x8 Aa2h = LDW(q0,2,0), Aa2l = LDW(q0,2,1), Aa3h = LDW(q0,3,0), Aa3l = LDW(q0,3,1);
  bf16x8 Aa4h = LDW(q0,4,0), Aa4l = LDW(q0,4,1);
  bf16x8 Ab0h = LDW(q1,0,0), Ab0l = LDW(q1,0,1), Ab1h = LDW(q1,1,0), Ab1l = LDW(q1,1,1);
  bf16x8 Ab2h = LDW(q1,2,0), Ab2l = LDW(q1,2,1), Ab3h = LDW(q1,3,0), Ab3l = LDW(q1,3,1);
  bf16x8 Ab4h = LDW(q1,4,0), Ab4l = LDW(q1,4,1);
#undef LDW
  asm volatile("" : "+v"(Aa0h), "+v"(Aa0l), "+v"(Aa1h), "+v"(Aa1l), "+v"(Aa2h),
                    "+v"(Aa2l), "+v"(Aa3h), "+v"(Aa3l), "+v"(Aa4h), "+v"(Aa4l),
                    "+v"(Ab0h), "+v"(Ab0l), "+v"(Ab1h), "+v"(Ab1l), "+v"(Ab2h),
                    "+v"(Ab2l), "+v"(Ab3h), "+v"(Ab3l), "+v"(Ab4h), "+v"(Ab4l));

  // ---- per-cell state (threads 0..255: cell (cb, cu))
  const int cb = tid & 15, cu = (tid >> 4) & 15;
  const int gb = bg * 16 + cb, hu = ug * 16 + cu;
  float c_reg = 0.f, bsq[4] = {0.f, 0.f, 0.f, 0.f};
  int mylen = -1;
  if (tid < 256) {
    c_reg = c0[(size_t)gb * HID + hu];
    mylen = len[gb];
    #pragma unroll
    for (int q = 0; q < 4; ++q) bsq[q] = bih[q * HID + hu] + bhh[q * HID + hu];
  }

  unsigned* myflags = flags + bg * 32;
  unsigned* xcds = flags + 256;
  unsigned* ctr  = flags + 512;

  // ---- one-time XCD consensus: fast path iff all 32 peers share our XCD
  unsigned myxcd;
  asm volatile("s_getreg_b32 %0, hwreg(HW_REG_XCC_ID)" : "=s"(myxcd));
  if (tid == 0) {
    __hip_atomic_store(xcds + blk, myxcd, __ATOMIC_RELAXED, __HIP_MEMORY_SCOPE_AGENT);
    asm volatile("s_waitcnt vmcnt(0)" ::: "memory");
    __hip_atomic_fetch_add(ctr, 1u, __ATOMIC_RELAXED, __HIP_MEMORY_SCOPE_AGENT);
    while (__hip_atomic_load(ctr, __ATOMIC_RELAXED, __HIP_MEMORY_SCOPE_AGENT) < NBLK)
      __builtin_amdgcn_s_sleep(4);
  }
  __syncthreads();
  {
    unsigned ok = 1;
    if (tid < 32) {
      unsigned x = __hip_atomic_load(xcds + (tid * 8 + bg), __ATOMIC_RELAXED,
                                     __HIP_MEMORY_SCOPE_AGENT);
      ok = (x == myxcd) ? 1u : 0u;
    }
    if (tid < 64) {
      unsigned long long m = __ballot(ok != 0);
      if (tid == 0) s_fast = (m == ~0ull) ? 1u : 0u;
    }
  }
  __syncthreads();
  const bool fast = (s_fast != 0);

  for (int t = 0; t < T_STEPS; ++t) {
    // ---- x stage (h-independent): 8KB straight copy into LDS planes (k<128)
    {
      const uint4* xps = (const uint4*)(xp + (size_t)(t * 8 + bg) * 4096);
      uint4 xa = xps[tid];
      int p = tid >> 8, c = (tid >> 4) & 15, kc = tid & 15;
      *(uint4*)(zpl + (p * 16 + c) * PK + kc * 8) = xa;
    }

    // ---- wait for the 32 peer blocks of this bg to finish step t-1
    if (t) {
      if (tid < 32) {
        const unsigned* fp = myflags + tid;
        if (fast) {
          unsigned v;
          do {
            asm volatile("global_load_dword %0, %1, off sc0\n\ts_waitcnt vmcnt(0)"
                         : "=v"(v) : "v"(fp) : "memory");
          } while (v < (unsigned)t);
        } else {
          while (__hip_atomic_load(fp, __ATOMIC_RELAXED,
                                   __HIP_MEMORY_SCOPE_AGENT) < (unsigned)t)
            __builtin_amdgcn_s_sleep(1);
        }
      }
      __syncthreads();
    }
    const unsigned* hsrc = ((t & 1) ? hp1 : hp0) + (size_t)bg * 8192;
    unsigned*       hdst = ((t & 1) ? hp0 : hp1) + (size_t)bg * 8192;

    // ---- h load + stage into planes (k>=128)
    unsigned long long hch[8];
    const unsigned long long* hq = (const unsigned long long*)hsrc;
    if (fast) {
      asm volatile("buffer_inv" ::: "memory");   // L1-only invalidate; h is in our XCD L2
      #pragma unroll
      for (int j = 0; j < 8; ++j) hch[j] = hq[j * 512 + tid];
    } else {
      #pragma unroll
      for (int j = 0; j < 8; ++j)
        hch[j] = __hip_atomic_load(hq + j * 512 + tid, __ATOMIC_RELAXED,
                                   __HIP_MEMORY_SCOPE_AGENT);
    }
    #pragma unroll
    for (int j = 0; j < 8; ++j) {
      int ci = j * 512 + tid;
      int c = ci >> 8, kp = ci & 255;
      unsigned w0 = (unsigned)hch[j], w1 = (unsigned)(hch[j] >> 32);
      unsigned hipair = (w0 & 0xFFFFu) | (w1 << 16);
      unsigned lopair = (w0 >> 16) | (w1 & 0xFFFF0000u);
      *(unsigned*)(zpl + c * PK + 128 + 2 * kp)        = hipair;
      *(unsigned*)(zpl + (16 + c) * PK + 128 + 2 * kp) = lopair;
    }
    __syncthreads();

    // ---- MFMA phase: 2 gate-tiles x 5 ksteps x 3 split products
    f32x4 acc0 = {0, 0, 0, 0}, acc1 = {0, 0, 0, 0};
#define KSTEP(s_, AH0, AL0, AH1, AL1)                                          \
  {                                                                            \
    int ka = kq * 160 + (s_) * 32 + gch * 8;                                   \
    bf16x8 Bh = *(const bf16x8*)(zpl + cB * PK + ka);                          \
    bf16x8 Bl = *(const bf16x8*)(zpl + (16 + cB) * PK + ka);                   \
    acc0 = __builtin_amdgcn_mfma_f32_16x16x32_bf16(AH0, Bh, acc0, 0, 0, 0);    \
    acc0 = __builtin_amdgcn_mfma_f32_16x16x32_bf16(AH0, Bl, acc0, 0, 0, 0);    \
    acc0 = __builtin_amdgcn_mfma_f32_16x16x32_bf16(AL0, Bh, acc0, 0, 0, 0);    \
    acc1 = __builtin_amdgcn_mfma_f32_16x16x32_bf16(AH1, Bh, acc1, 0, 0, 0);    \
    acc1 = __builtin_amdgcn_mfma_f32_16x16x32_bf16(AH1, Bl, acc1, 0, 0, 0);    \
    acc1 = __builtin_amdgcn_mfma_f32_16x16x32_bf16(AL1, Bh, acc1, 0, 0, 0);    \
  }
    KSTEP(0, Aa0h, Aa0l, Ab0h, Ab0l)
    KSTEP(1, Aa1h, Aa1l, Ab1h, Ab1l)
    KSTEP(2, Aa2h, Aa2l, Ab2h, Ab2l)
    KSTEP(3, Aa3h, Aa3l, Ab3h, Ab3l)
    KSTEP(4, Aa4h, Aa4l, Ab4h, Ab4l)
#undef KSTEP

    // ---- dump partial gates: C layout col=l&15, row(unit)=(l>>4)*4+reg
    #pragma unroll
    for (int rr = 0; rr < 4; ++rr) {
      gates[((kq * 4 + q0) * 16 + gch * 4 + rr) * GSTR + cB] = acc0[rr];
      gates[((kq * 4 + q1) * 16 + gch * 4 + rr) * GSTR + cB] = acc1[rr];
    }
    __syncthreads();

    // ---- cell update (threads 0..255, one (cb,cu) each)
    if (tid < 256) {
      float s4[4];
      #pragma unroll
      for (int q = 0; q < 4; ++q) {
        float s = bsq[q];
        #pragma unroll
        for (int kp = 0; kp < 4; ++kp)
          s += gates[((kp * 4 + q) * 16 + cu) * GSTR + cb];
        s4[q] = s;
      }
      float iv = fsigmoid(s4[0]);
      float fv = fsigmoid(s4[1]);
      float gv = ftanh(s4[2]);
      float ov = fsigmoid(s4[3]);
      c_reg = fv * c_reg + iv * gv;
      float h2 = ov * ftanh(c_reg);
      unsigned short hh = bf_hi(h2);
      unsigned short ll = bf_hi(h2 - bf_val(hh));
      unsigned hv = (unsigned)hh | ((unsigned)ll << 16);
      if (fast) hdst[(size_t)cb * 512 + hu] = hv;   // write-through -> XCD L2
      else __hip_atomic_store(hdst + (size_t)cb * 512 + hu, hv,
                              __ATOMIC_RELAXED, __HIP_MEMORY_SCOPE_AGENT);
      if (t == mylen - 1) out[(size_t)gb * HID + hu] = h2;
    }

    __syncthreads();   // vmcnt(0) drain: h stores are in L2 before flag store
    if (tid == 0) {
      if (fast) *(volatile unsigned*)(myflags + ug) = (unsigned)(t + 1);
      else __hip_atomic_store(myflags + ug, (unsigned)(t + 1),
                              __ATOMIC_RELAXED, __HIP_MEMORY_SCOPE_AGENT);
    }
  }
}

// ---------------- launch ----------------
extern "C" void kernel_launch(void* const* d_in, const int* in_sizes, int n_in,
                              void* d_out, int out_size, void* d_ws, size_t ws_size,
                              hipStream_t stream)
{
  const float* inputs = (const float*)d_in[0];
  const int*   len    = (const int*)  d_in[1];
  const float* h0     = (const float*)d_in[2];
  const float* c0     = (const float*)d_in[3];
  const float* Wih    = (const float*)d_in[4];
  const float* Whh    = (const float*)d_in[5];
  const float* bih    = (const float*)d_in[6];
  const float* bhh    = (const float*)d_in[7];
  float* out = (float*)d_out;

  char* p = (char*)d_ws;
  unsigned short* xp = (unsigned short*)p; p += (size_t)T_STEPS * 8 * 4096 * 2;      // 64 MB
  unsigned short* wf = (unsigned short*)p; p += (size_t)2560 * 2 * 64 * 8 * 2;       // 5 MB
  unsigned* hp0 = (unsigned*)p;  p += (size_t)8 * 16 * 512 * 4;                      // 256 KB
  unsigned* hp1 = (unsigned*)p;  p += (size_t)8 * 16 * 512 * 4;                      // 256 KB
  unsigned* flags = (unsigned*)p; p += 544 * 4;   // 256 flags + 256 xcds + ctr

  (void)hipFuncSetAttribute((const void*)k_persist,
                            hipFuncAttributeMaxDynamicSharedMemorySize, SMEM_BYTES);

  k_prep_x<<<T_STEPS * 8, 256, 0, stream>>>(inputs, xp);
  k_prep_w<<<2560, 64, 0, stream>>>(Wih, Whh, wf);
  k_prep_h<<<256, 256, 0, stream>>>(h0, hp0, flags);

  void* args[] = {(void*)&xp, (void*)&wf, (void*)&bih, (void*)&bhh,
                  (void*)&hp0, (void*)&hp1, (void*)&c0, (void*)&len,
                  (void*)&out, (void*)&flags};
  (void)hipLaunchCooperativeKernel((void*)k_persist, dim3(NBLK), dim3(NTHR),
                                   args, SMEM_BYTES, stream);
}